// Round 12
// baseline (772.785 us; speedup 1.0000x reference)
//
#include <hip/hip_runtime.h>
#include <hip/hip_bf16.h>

// WindowAttentionV2: B_NW=2048, N=64, DIM=512, NH=16, DH=32, HID=384, NW=64
// v10: qkv/proj -> 256x256 tile, BK=32, 512 thr (8 waves, wave=128x64), counted-vmcnt(4),
//      XOR-swizzled LDS (read-side ^((row>>1)&7)<<4, gload_lds source pre-swizzled - involution).
//      Attn / converts / comb unchanged from v9.

typedef __bf16 bf16;
typedef __bf16 v4bf __attribute__((ext_vector_type(4)));
typedef __bf16 v8bf __attribute__((ext_vector_type(8)));
typedef float  v4f  __attribute__((ext_vector_type(4)));

// ---------------- K0a: x fp32 -> bf16 (grid-stride) ----------------
__global__ void convert_x_kernel(const float* __restrict__ x, bf16* __restrict__ xbf) {
    const int stride = gridDim.x * 256;
    for (size_t idx = blockIdx.x * 256 + threadIdx.x; idx < 8388608; idx += stride) {
        const float4* xv = (const float4*)x;
        float4 v0 = xv[idx * 2];
        float4 v1 = xv[idx * 2 + 1];
        v8bf o = { (bf16)v0.x, (bf16)v0.y, (bf16)v0.z, (bf16)v0.w,
                   (bf16)v1.x, (bf16)v1.y, (bf16)v1.z, (bf16)v1.w };
        *(v8bf*)(xbf + idx * 8) = o;
    }
}

// ---------------- K0b: weights -> transposed bf16 ----------------
__global__ void convert_w_kernel(const float* __restrict__ wqkv, const float* __restrict__ wout,
                                 bf16* __restrict__ Wt, bf16* __restrict__ WoT) {
    int idx = blockIdx.x * 256 + threadIdx.x;        // 786,432 threads
    Wt[idx] = (bf16)wqkv[(idx & 511) * 1536 + (idx >> 9)];
    if (idx < 262144) WoT[idx] = (bf16)wout[(idx & 511) * 512 + (idx >> 9)];
}

// ---------------- K1a: meta-MLP bias[h][i][j] ----------------
__global__ void bias_kernel(const float* __restrict__ rel_log, const float* __restrict__ w1,
                            const float* __restrict__ b1, const float* __restrict__ w2,
                            const float* __restrict__ b2, float* __restrict__ bias) {
    int p = blockIdx.x * 256 + threadIdx.x;          // (i,j) pair, 4096 total
    float ra = rel_log[p * 2 + 0];
    float rb = rel_log[p * 2 + 1];
    float acc[16];
    #pragma unroll
    for (int t = 0; t < 16; ++t) acc[t] = 0.f;
    for (int kk = 0; kk < 384; ++kk) {
        float hv = fmaxf(ra * w1[kk] + rb * w1[384 + kk] + b1[kk], 0.f);
        #pragma unroll
        for (int t = 0; t < 16; ++t) acc[t] += hv * w2[kk * 16 + t];
    }
    #pragma unroll
    for (int t = 0; t < 16; ++t) bias[t * 4096 + p] = acc[t] + b2[t];
}

// ---------------- K1b: comb swizzled for the SWAPPED (S^T) frag layout ----------------
__global__ void comb_kernel(const float* __restrict__ bias, const float* __restrict__ mask,
                            float* __restrict__ comb) {
    int idx = blockIdx.x * 256 + threadIdx.x;        // 4,194,304 threads (16384 blocks)
    int t = idx & 4095, wh = idx >> 12;
    int w = wh >> 4, h = wh & 15;
    int ji = t >> 8, rem = t & 255;
    int j = ji >> 2, i = ji & 3;
    int q16 = rem >> 2, r = t & 3;
    int lq = q16 >> 4, lm = q16 & 15;
    int p = (i * 16 + lm) * 64 + j * 16 + lq * 4 + r;
    comb[idx] = bias[h * 4096 + p] + mask[w * 4096 + p];
}

// swizzle: involution on 16KB tile (256 rows x 64B); mask bits 4-6 from bits 7-9.
__device__ __forceinline__ int swz(int o) { return o ^ (((o >> 7) & 7) << 4); }

// ---------------- K2: qkv GEMM, 256x256, counted-vmcnt, swizzled LDS ----------------
// Grid 6*W/4... = (W/4 m-tiles) x 6 nb = 3072 blocks @ W=2048. 512 thr, wave wv: wr=wv>>2, wc=wv&3.
// Outputs (UNNORMALIZED): q_ws/k_ws [bw*16+h][n][dh] bf16, v_ws [bw*16+h][dh][n] bf16.
__global__ __launch_bounds__(512, 1) void qkv_gemm_kernel(
    const bf16* __restrict__ xbf,   // [131072][512] bf16
    const bf16* __restrict__ Wt,    // [1536][512]
    bf16* __restrict__ q_ws, bf16* __restrict__ k_ws, bf16* __restrict__ v_ws)
{
    __shared__ alignas(16) char Alds[2][16384];     // 256 x 32 bf16, swizzled
    __shared__ alignas(16) char Blds[2][16384];
    const int bid = blockIdx.x, nwg = gridDim.x;
    const int wid = (bid & 7) * (nwg >> 3) + (bid >> 3);   // XCD-bijective (nwg%8==0)
    const int nb = wid % 6, mb = wid / 6;                  // mb in [0, 512)

    const int t = threadIdx.x;
    const int wv = t >> 6, lane = t & 63, lq = lane >> 4, lm = lane & 15;
    const int wr = wv >> 2, wc = wv & 3;                   // wave tile: rows wr*128, cols wc*64

    const char* aBase = (const char*)xbf + (size_t)mb * 256 * 1024;
    const char* bBase = (const char*)Wt + (size_t)nb * 256 * 1024;

    // per-thread 2 stage chunks of 16B: LDS offsets o = p*8192 + t*16 (wave-uniform base + lane*16)
    int so[2], srow[2], scol[2];
    #pragma unroll
    for (int p = 0; p < 2; ++p) {
        so[p] = p * 8192 + t * 16;
        int s = swz(so[p]);
        srow[p] = s >> 6; scol[p] = s & 63;
    }

    auto stage = [&](int buf, int kt) {   // 4 gload_lds per thread (2 A + 2 B)
        #pragma unroll
        for (int p = 0; p < 2; ++p) {
            __builtin_amdgcn_global_load_lds(
                (const __attribute__((address_space(1))) void*)(aBase + (size_t)srow[p] * 1024 + kt * 64 + scol[p]),
                (__attribute__((address_space(3))) void*)(&Alds[buf][0] + (wv * 1024 + (t & 63) * 16) + (so[p] & 8192)),
                16, 0, 0);
            __builtin_amdgcn_global_load_lds(
                (const __attribute__((address_space(1))) void*)(bBase + (size_t)srow[p] * 1024 + kt * 64 + scol[p]),
                (__attribute__((address_space(3))) void*)(&Blds[buf][0] + (wv * 1024 + (t & 63) * 16) + (so[p] & 8192)),
                16, 0, 0);
        }
    };

    v4f acc[8][4];
    #pragma unroll
    for (int i = 0; i < 8; ++i)
        #pragma unroll
        for (int j = 0; j < 4; ++j) acc[i][j] = v4f{0.f, 0.f, 0.f, 0.f};

    // precomputed swizzled read offsets
    int aoff[8], boff[4];
    #pragma unroll
    for (int i = 0; i < 8; ++i) {
        int row = wr * 128 + i * 16 + lm;
        aoff[i] = (row * 64 + lq * 16) ^ (((row >> 1) & 7) << 4);
    }
    #pragma unroll
    for (int j = 0; j < 4; ++j) {
        int row = wc * 64 + j * 16 + lm;
        boff[j] = (row * 64 + lq * 16) ^ (((row >> 1) & 7) << 4);
    }

    stage(0, 0);
    #pragma unroll 1
    for (int kt = 0; kt < 16; ++kt) {
        if (kt < 15) {
            stage((kt + 1) & 1, kt + 1);               // next tile stays in flight across barriers
            asm volatile("s_waitcnt vmcnt(4)" ::: "memory");
        } else {
            asm volatile("s_waitcnt vmcnt(0)" ::: "memory");
        }
        __builtin_amdgcn_s_barrier();
        __builtin_amdgcn_sched_barrier(0);
        const char* Ab = &Alds[kt & 1][0];
        const char* Bb = &Blds[kt & 1][0];
        v8bf af[8], bfj[4];
        #pragma unroll
        for (int i = 0; i < 8; ++i) af[i] = *(const v8bf*)(Ab + aoff[i]);
        #pragma unroll
        for (int j = 0; j < 4; ++j) bfj[j] = *(const v8bf*)(Bb + boff[j]);
        #pragma unroll
        for (int i = 0; i < 8; ++i)
            #pragma unroll
            for (int j = 0; j < 4; ++j)
                acc[i][j] = __builtin_amdgcn_mfma_f32_16x16x32_bf16(af[i], bfj[j], acc[i][j], 0, 0, 0);
        __builtin_amdgcn_s_barrier();
    }

    // epilogue: local row = wr*128 + i*16 + lq*4 + r -> bw = mb*4 + wr*2 + (i>>2), n = (i&3)*16 + lq*4 + r
    // col c = nb*256 + wc*64 + j*16 + lm; nb<2: q, nb<4: k, else v. h = (nb&1)*8 + wc*2 + (j>>1).
    if (nb < 4) {
        bf16* dst = (nb < 2) ? q_ws : k_ws;
        #pragma unroll
        for (int tpair = 0; tpair < 2; ++tpair) {
            const int h = (nb & 1) * 8 + wc * 2 + tpair;
            #pragma unroll
            for (int i = 0; i < 8; ++i) {
                const int bw = mb * 4 + wr * 2 + (i >> 2);
                #pragma unroll
                for (int r = 0; r < 4; ++r) {
                    int n = (i & 3) * 16 + lq * 4 + r;
                    size_t base = ((size_t)(bw * 16 + h) * 64 + n) * 32;
                    dst[base + lm]      = (bf16)acc[i][2 * tpair][r];
                    dst[base + 16 + lm] = (bf16)acc[i][2 * tpair + 1][r];
                }
            }
        }
    } else {
        #pragma unroll
        for (int j = 0; j < 4; ++j) {
            const int h = 8 + wc * 2 + (j >> 1);       // nb==4 -> h 8..15? no: (nb&1)*8 with nb in {4,5}
            const int h2 = ((nb - 4) & 1) * 8 + wc * 2 + (j >> 1);
            const int dh = (j & 1) * 16 + lm;
            (void)h;
            #pragma unroll
            for (int i = 0; i < 8; ++i) {
                const int bw = mb * 4 + wr * 2 + (i >> 2);
                v4bf pv = { (bf16)acc[i][j][0], (bf16)acc[i][j][1],
                            (bf16)acc[i][j][2], (bf16)acc[i][j][3] };
                *(v4bf*)(v_ws + ((size_t)(bw * 16 + h2) * 32 + dh) * 64 + (i & 3) * 16 + lq * 4) = pv;
            }
        }
    }
}

// ---------------- K3: attention, swapped QK^T, frag-local norm, 1 head/wave ----------------
__global__ __launch_bounds__(256) void attn_kernel(
    const bf16* __restrict__ q_ws,   // [bw*16+h][64][32] unnormalized
    const bf16* __restrict__ k_ws,
    const bf16* __restrict__ v_ws,   // [bw*16+h][32][64]
    const float* __restrict__ comb,  // [64][16][4096] swizzled for S^T frags
    const float* __restrict__ tau,   // [16]
    int wofs,
    bf16* __restrict__ attn_out)     // [rows][512]
{
    __shared__ alignas(16) bf16 P_all[4][64 * 72];
    const int blk = blockIdx.x;
    const int b = blk >> 2, g = blk & 3;
    const int tid = threadIdx.x;
    const int wv = tid >> 6, lane = tid & 63, lq = lane >> 4, lm = lane & 15;
    const int h = g * 4 + wv;
    const v4f z4 = {0.f, 0.f, 0.f, 0.f};

    bf16* P = P_all[wv];
    const size_t qk_base = (size_t)(b * 16 + h) * 64 * 32;
    const float* comb_hw = comb + ((size_t)(((wofs + b) & 63) * 16 + h)) * 4096
                                + (lq * 16 + lm) * 4;
    const float tau_h = tau[h];

    v8bf qf[4], kf[4];
    #pragma unroll
    for (int i = 0; i < 4; ++i)
        qf[i] = *(const v8bf*)(q_ws + qk_base + (i * 16 + lm) * 32 + lq * 8);
    #pragma unroll
    for (int j = 0; j < 4; ++j)
        kf[j] = *(const v8bf*)(k_ws + qk_base + (j * 16 + lm) * 32 + lq * 8);

    #pragma unroll
    for (int i = 0; i < 4; ++i) {
        float a = 0.f;
        #pragma unroll
        for (int e = 0; e < 8; ++e) { float f = (float)qf[i][e]; a = fmaf(f, f, a); }
        a += __shfl_xor(a, 16); a += __shfl_xor(a, 32);
        float sc = tau_h / fmaxf(sqrtf(a), 1e-12f);
        #pragma unroll
        for (int e = 0; e < 8; ++e) qf[i][e] = (bf16)((float)qf[i][e] * sc);
    }
    #pragma unroll
    for (int j = 0; j < 4; ++j) {
        float a = 0.f;
        #pragma unroll
        for (int e = 0; e < 8; ++e) { float f = (float)kf[j][e]; a = fmaf(f, f, a); }
        a += __shfl_xor(a, 16); a += __shfl_xor(a, 32);
        float sc = 1.0f / fmaxf(sqrtf(a), 1e-12f);
        #pragma unroll
        for (int e = 0; e < 8; ++e) kf[j][e] = (bf16)((float)kf[j][e] * sc);
    }

    v4f st[4][4];
    #pragma unroll
    for (int j = 0; j < 4; ++j)
        #pragma unroll
        for (int i = 0; i < 4; ++i)
            st[j][i] = __builtin_amdgcn_mfma_f32_16x16x32_bf16(kf[j], qf[i], z4, 0, 0, 0);

    #pragma unroll
    for (int j = 0; j < 4; ++j)
        #pragma unroll
        for (int i = 0; i < 4; ++i) {
            float4 cv = *(const float4*)(comb_hw + (j * 4 + i) * 256);
            st[j][i][0] += cv.x; st[j][i][1] += cv.y;
            st[j][i][2] += cv.z; st[j][i][3] += cv.w;
        }

    #pragma unroll
    for (int i = 0; i < 4; ++i) {
        float mx = st[0][i][0];
        #pragma unroll
        for (int j = 0; j < 4; ++j)
            #pragma unroll
            for (int r = 0; r < 4; ++r) mx = fmaxf(mx, st[j][i][r]);
        mx = fmaxf(mx, __shfl_xor(mx, 16));
        mx = fmaxf(mx, __shfl_xor(mx, 32));
        float sm = 0.f;
        #pragma unroll
        for (int j = 0; j < 4; ++j)
            #pragma unroll
            for (int r = 0; r < 4; ++r) {
                float e = __expf(st[j][i][r] - mx);
                st[j][i][r] = e; sm += e;
            }
        sm += __shfl_xor(sm, 16); sm += __shfl_xor(sm, 32);
        float rcp = 1.0f / sm;
        #pragma unroll
        for (int j = 0; j < 4; ++j) {
            v4bf pv = { (bf16)(st[j][i][0] * rcp), (bf16)(st[j][i][1] * rcp),
                        (bf16)(st[j][i][2] * rcp), (bf16)(st[j][i][3] * rcp) };
            *(v4bf*)(P + (i * 16 + lm) * 72 + j * 16 + lq * 4) = pv;
        }
    }

    const size_t v_base = (size_t)(b * 16 + h) * 32 * 64;
    v4f o[4][2];
    #pragma unroll
    for (int i = 0; i < 4; ++i)
        #pragma unroll
        for (int nt = 0; nt < 2; ++nt) o[i][nt] = z4;
    #pragma unroll
    for (int kk = 0; kk < 2; ++kk) {
        v8bf vf[2], pf[4];
        #pragma unroll
        for (int nt = 0; nt < 2; ++nt)
            vf[nt] = *(const v8bf*)(v_ws + v_base + (nt * 16 + lm) * 64 + kk * 32 + lq * 8);
        #pragma unroll
        for (int i = 0; i < 4; ++i)
            pf[i] = *(const v8bf*)(P + (i * 16 + lm) * 72 + kk * 32 + lq * 8);
        #pragma unroll
        for (int i = 0; i < 4; ++i)
            #pragma unroll
            for (int nt = 0; nt < 2; ++nt)
                o[i][nt] = __builtin_amdgcn_mfma_f32_16x16x32_bf16(pf[i], vf[nt], o[i][nt], 0, 0, 0);
    }
    #pragma unroll
    for (int i = 0; i < 4; ++i)
        #pragma unroll
        for (int nt = 0; nt < 2; ++nt)
            #pragma unroll
            for (int r = 0; r < 4; ++r)
                attn_out[(size_t)(b * 64 + i * 16 + lq * 4 + r) * 512 + h * 32 + nt * 16 + lm] =
                    (bf16)o[i][nt][r];
}

// ---------------- K4: out-projection GEMM, 256x256, counted-vmcnt, swizzled LDS ----------------
__global__ __launch_bounds__(512, 1) void proj_gemm_kernel(
    const bf16* __restrict__ A,     // [131072][512] attn_out
    const bf16* __restrict__ Bt,    // [512][512] WoT
    const float* __restrict__ b_out,
    float* __restrict__ out)        // [131072][512]
{
    __shared__ alignas(16) char Alds[2][16384];
    __shared__ alignas(16) char Blds[2][16384];
    const int bid = blockIdx.x;                       // 1024 blocks
    const int wid = (bid & 7) * 128 + (bid >> 3);     // XCD swizzle (1024%8==0)
    const int nb = wid & 1, mb = wid >> 1;            // nb fastest: A-tile reuse
    const int t = threadIdx.x;
    const int wv = t >> 6, lane = t & 63, lq = lane >> 4, lm = lane & 15;
    const int wr = wv >> 2, wc = wv & 3;

    const char* aBase = (const char*)A + (size_t)mb * 256 * 1024;
    const char* bBase = (const char*)Bt + (size_t)nb * 256 * 1024;

    int so[2], srow[2], scol[2];
    #pragma unroll
    for (int p = 0; p < 2; ++p) {
        so[p] = p * 8192 + t * 16;
        int s = swz(so[p]);
        srow[p] = s >> 6; scol[p] = s & 63;
    }

    auto stage = [&](int buf, int kt) {
        #pragma unroll
        for (int p = 0; p < 2; ++p) {
            __builtin_amdgcn_global_load_lds(
                (const __attribute__((address_space(1))) void*)(aBase + (size_t)srow[p] * 1024 + kt * 64 + scol[p]),
                (__attribute__((address_space(3))) void*)(&Alds[buf][0] + (wv * 1024 + (t & 63) * 16) + (so[p] & 8192)),
                16, 0, 0);
            __builtin_amdgcn_global_load_lds(
                (const __attribute__((address_space(1))) void*)(bBase + (size_t)srow[p] * 1024 + kt * 64 + scol[p]),
                (__attribute__((address_space(3))) void*)(&Blds[buf][0] + (wv * 1024 + (t & 63) * 16) + (so[p] & 8192)),
                16, 0, 0);
        }
    };

    v4f acc[8][4];
    #pragma unroll
    for (int i = 0; i < 8; ++i)
        #pragma unroll
        for (int j = 0; j < 4; ++j) acc[i][j] = v4f{0.f, 0.f, 0.f, 0.f};

    int aoff[8], boff[4];
    #pragma unroll
    for (int i = 0; i < 8; ++i) {
        int row = wr * 128 + i * 16 + lm;
        aoff[i] = (row * 64 + lq * 16) ^ (((row >> 1) & 7) << 4);
    }
    #pragma unroll
    for (int j = 0; j < 4; ++j) {
        int row = wc * 64 + j * 16 + lm;
        boff[j] = (row * 64 + lq * 16) ^ (((row >> 1) & 7) << 4);
    }

    stage(0, 0);
    #pragma unroll 1
    for (int kt = 0; kt < 16; ++kt) {
        if (kt < 15) {
            stage((kt + 1) & 1, kt + 1);
            asm volatile("s_waitcnt vmcnt(4)" ::: "memory");
        } else {
            asm volatile("s_waitcnt vmcnt(0)" ::: "memory");
        }
        __builtin_amdgcn_s_barrier();
        __builtin_amdgcn_sched_barrier(0);
        const char* Ab = &Alds[kt & 1][0];
        const char* Bb = &Blds[kt & 1][0];
        v8bf af[8], bfj[4];
        #pragma unroll
        for (int i = 0; i < 8; ++i) af[i] = *(const v8bf*)(Ab + aoff[i]);
        #pragma unroll
        for (int j = 0; j < 4; ++j) bfj[j] = *(const v8bf*)(Bb + boff[j]);
        #pragma unroll
        for (int i = 0; i < 8; ++i)
            #pragma unroll
            for (int j = 0; j < 4; ++j)
                acc[i][j] = __builtin_amdgcn_mfma_f32_16x16x32_bf16(af[i], bfj[j], acc[i][j], 0, 0, 0);
        __builtin_amdgcn_s_barrier();
    }

    #pragma unroll
    for (int j = 0; j < 4; ++j) {
        int col = nb * 256 + wc * 64 + j * 16 + lm;
        float bo = b_out[col];
        #pragma unroll
        for (int i = 0; i < 8; ++i)
            #pragma unroll
            for (int r = 0; r < 4; ++r)
                out[(size_t)(mb * 256 + wr * 128 + i * 16 + lq * 4 + r) * 512 + col] = acc[i][j][r] + bo;
    }
}

// ---------------- launch ----------------
extern "C" void kernel_launch(void* const* d_in, const int* in_sizes, int n_in,
                              void* d_out, int out_size, void* d_ws, size_t ws_size,
                              hipStream_t stream) {
    (void)in_sizes; (void)n_in; (void)out_size;
    const float* x       = (const float*)d_in[0];
    const float* mask    = (const float*)d_in[1];
    const float* w_qkv   = (const float*)d_in[2];
    const float* tau     = (const float*)d_in[3];
    const float* mlp_w1  = (const float*)d_in[4];
    const float* mlp_b1  = (const float*)d_in[5];
    const float* mlp_w2  = (const float*)d_in[6];
    const float* mlp_b2  = (const float*)d_in[7];
    const float* w_out   = (const float*)d_in[8];
    const float* b_out   = (const float*)d_in[9];
    const float* rel_log = (const float*)d_in[10];
    float* out = (float*)d_out;

    char* ws = (char*)d_ws;
    bf16*  Wt     = (bf16*)(ws);                     // 1,572,864 B
    bf16*  WoT    = (bf16*)(ws + 1572864);           //   524,288 B
    float* bias   = (float*)(ws + 2097152);          //   262,144 B
    float* comb   = (float*)(ws + 2359296);          //  16,777,216 B
    bf16*  shared = (bf16*)(ws + 19136512);          // 134,217,728 B  (xbf, later attn_out)
    char*  qkv_base = ws + 153354240;

    size_t avail = (ws_size > 153354240ULL) ? ws_size - 153354240ULL : 0;
    int W = 2048;                                    // 556 MB total; ws = 1 GiB (round-5 poison)
    while (W > 128 && (size_t)W * 196608ULL > avail) W >>= 1;
    const size_t qkbuf = (size_t)W * 65536;
    bf16* qb = (bf16*)qkv_base;
    bf16* kb = (bf16*)(qkv_base + qkbuf);
    bf16* vb = (bf16*)(qkv_base + 2 * qkbuf);

    convert_w_kernel<<<3072, 256, 0, stream>>>(w_qkv, w_out, Wt, WoT);
    bias_kernel<<<16, 256, 0, stream>>>(rel_log, mlp_w1, mlp_b1, mlp_w2, mlp_b2, bias);
    comb_kernel<<<16384, 256, 0, stream>>>(bias, mask, comb);
    convert_x_kernel<<<2048, 256, 0, stream>>>(x, shared);

    const int nchunk = 2048 / W;
    for (int c = 0; c < nchunk; ++c) {
        bf16* slice = shared + (size_t)c * W * 64 * 512;
        qkv_gemm_kernel<<<(6 * W) / 4, 512, 0, stream>>>(slice, Wt, qb, kb, vb);
        attn_kernel<<<4 * W, 256, 0, stream>>>(qb, kb, vb, comb, tau, c * W, slice);
    }
    proj_gemm_kernel<<<1024, 512, 0, stream>>>(shared, WoT, b_out, out);
}